// Round 4
// baseline (785.823 us; speedup 1.0000x reference)
//
#include <hip/hip_runtime.h>
#include <hip/hip_bf16.h>
#include <math.h>

// ---------------------------------------------------------------------------
// Dims (fixed per reference)
// ---------------------------------------------------------------------------
#define BATCH   16384
#define D_IN    1024
#define H1_DIM  512
#define H2_DIM  256
#define H3_DIM  128
#define D_CBP   2048
#define H_C     1024
#define CLASSES 10
#define SLOPE   0.2f

#define NPAIRS    (H3_DIM * H3_DIM)      // 16384
#define PAIRS_CAP (NPAIRS + 3 * D_CBP)   // 22528 (counts padded to x4)
#define DUMMY_IDX 16384                  // O[DUMMY_IDX] == 0

typedef short v8s __attribute__((ext_vector_type(8)));
typedef float v4f __attribute__((ext_vector_type(4)));
typedef unsigned short u16;
typedef unsigned int   u32;

__device__ __forceinline__ float b2f(unsigned short u) {
  return __uint_as_float(((unsigned)u) << 16);
}
__device__ __forceinline__ u16 f2b(float f) {
  __hip_bfloat16 h = __float2bfloat16(f);   // RNE
  return __builtin_bit_cast(unsigned short, h);
}

// async 16B global->LDS (direct-to-shared DMA). LDS dest = wave-uniform base
// + lane*16 -> LDS layout is forced packed lane-order.
__device__ __forceinline__ void g2l16(const void* g, void* l) {
  __builtin_amdgcn_global_load_lds(
      (const __attribute__((address_space(1))) void*)g,
      (__attribute__((address_space(3))) void*)l, 16, 0, 0);
}

// ---------------------------------------------------------------------------
// bf16 MFMA GEMM (m97 structure): C[M,N] = lrelu(A[M,K] @ Bt[N,K]^T + bias)
// Tile 128x128, BK=32, 256 threads (4 waves, 2x2 of 64x64), 16 MFMA/wave/step.
// Granule rotation swizzle applied at the GLOBAL address so both A- and
// B-fragment ds_read_b128 are exactly 2 lanes/bank (free).
// ---------------------------------------------------------------------------
__global__ __launch_bounds__(256) void gemm_bf16(
    const u16* __restrict__ A,   // [M][K] bf16
    const u16* __restrict__ Bt,  // [N][K] bf16  (weights pre-transposed)
    const float* __restrict__ bias,
    u16* __restrict__ C,         // [M][N] bf16
    int M, int N, int K)
{
  __shared__ __align__(16) short Asb[128 * 32];
  __shared__ __align__(16) short Bsb[128 * 32];

  const int tid  = threadIdx.x;
  const int wave = tid >> 6, lane = tid & 63;
  const int wm = wave >> 1, wn = wave & 1;
  const int u = lane & 15, quad = lane >> 4;
  const int m0 = blockIdx.y * 128, n0 = blockIdx.x * 128;

  const int g_log = ((lane & 3) - ((lane >> 3) & 3)) & 3;
  const int srow  = wave * 32 + (lane >> 2);
  const u16* gA0 = A  + (size_t)(m0 + srow)      * K + g_log * 8;
  const u16* gA1 = A  + (size_t)(m0 + srow + 16) * K + g_log * 8;
  const u16* gB0 = Bt + (size_t)(n0 + srow)      * K + g_log * 8;
  const u16* gB1 = Bt + (size_t)(n0 + srow + 16) * K + g_log * 8;
  short* lA0 = &Asb[(wave * 32)      * 32];
  short* lA1 = &Asb[(wave * 32 + 16) * 32];
  short* lB0 = &Bsb[(wave * 32)      * 32];
  short* lB1 = &Bsb[(wave * 32 + 16) * 32];

  const int gran = (quad + (u >> 1)) & 3;
  int offA[4], offB[4];
#pragma unroll
  for (int i = 0; i < 4; ++i) {
    offA[i] = (wm * 64 + i * 16 + u) * 32 + gran * 8;
    offB[i] = (wn * 64 + i * 16 + u) * 32 + gran * 8;
  }

  v4f acc[4][4];
#pragma unroll
  for (int i = 0; i < 4; ++i)
#pragma unroll
    for (int j = 0; j < 4; ++j) acc[i][j] = (v4f){0.f, 0.f, 0.f, 0.f};

  for (int k0 = 0; k0 < K; k0 += 32) {
    __syncthreads();
    g2l16(gA0 + k0, lA0);
    g2l16(gA1 + k0, lA1);
    g2l16(gB0 + k0, lB0);
    g2l16(gB1 + k0, lB1);
    __syncthreads();
    v8s a[4], b[4];
#pragma unroll
    for (int i = 0; i < 4; ++i) a[i] = *(const v8s*)&Asb[offA[i]];
#pragma unroll
    for (int j = 0; j < 4; ++j) b[j] = *(const v8s*)&Bsb[offB[j]];
#pragma unroll
    for (int i = 0; i < 4; ++i)
#pragma unroll
      for (int j = 0; j < 4; ++j)
        acc[i][j] = __builtin_amdgcn_mfma_f32_16x16x32_bf16(a[i], b[j], acc[i][j], 0, 0, 0);
  }

  // C/D layout (m89-verified): col = lane&15, row = quad*4 + reg
  float bcol[4];
#pragma unroll
  for (int j = 0; j < 4; ++j) bcol[j] = bias[n0 + wn * 64 + j * 16 + u];
#pragma unroll
  for (int i = 0; i < 4; ++i)
#pragma unroll
    for (int r = 0; r < 4; ++r) {
      const size_t ro = (size_t)(m0 + wm * 64 + i * 16 + quad * 4 + r) * N
                        + n0 + wn * 64 + u;
#pragma unroll
      for (int j = 0; j < 4; ++j) {
        float v = acc[i][j][r] + bcol[j];
        v = v >= 0.f ? v : SLOPE * v;
        C[ro + j * 16] = f2b(v);
      }
    }
}

// ---------------------------------------------------------------------------
// cast fp32 -> bf16
// ---------------------------------------------------------------------------
__global__ __launch_bounds__(256) void cast_bf16(
    const float* __restrict__ src, u16* __restrict__ dst, int n4)
{
  const int i = blockIdx.x * 256 + threadIdx.x;
  if (i < n4) {
    const float4 v = ((const float4*)src)[i];
    __align__(8) u16 o[4] = {f2b(v.x), f2b(v.y), f2b(v.z), f2b(v.w)};
    *(uint2*)(dst + (size_t)i * 4) = *(uint2*)o;
  }
}

// ---------------------------------------------------------------------------
// transpose + cast: W[K][N] fp32 -> Wt[N][K] bf16.
// ---------------------------------------------------------------------------
__global__ __launch_bounds__(256) void transpose_cast(
    const float* __restrict__ W, u16* __restrict__ Wt, int K, int N)
{
  __shared__ float tile[32][33];
  const int k0 = blockIdx.x * 32, n0 = blockIdx.y * 32;
  const int tx = threadIdx.x & 31, ty = threadIdx.x >> 5;
#pragma unroll
  for (int s = 0; s < 4; ++s) {
    const int k = ty * 4 + s;
    tile[k][tx] = W[(size_t)(k0 + k) * N + n0 + tx];
  }
  __syncthreads();
#pragma unroll
  for (int s = 0; s < 4; ++s) {
    const int n = ty * 4 + s;
    Wt[(size_t)(n0 + n) * K + k0 + tx] = f2b(tile[tx][n]);
  }
}

// ---------------------------------------------------------------------------
// CSR builder (one block): bins the 128x128 (i,j) pairs by
// k = (h1[i]+h2[j]) & 2047. Counts padded to x4 (dummies -> DUMMY_IDX, a
// zeroed O slot) so the gather runs in clean uint4 chunks that never
// straddle a bin. Stored pair value = XOR-swizzled O index.
// ---------------------------------------------------------------------------
__global__ __launch_bounds__(256) void build_csr(
    const int* __restrict__ h1, const int* __restrict__ h2,
    u32* __restrict__ pairs,     // [PAIRS_CAP]
    u32* __restrict__ offs)      // [D_CBP + 1]
{
  __shared__ u32 cnt[D_CBP];
  __shared__ u32 cur[D_CBP];
  __shared__ u32 partial[256];
  __shared__ int h1s[H3_DIM], h2s[H3_DIM];

  const int t = threadIdx.x;
  for (int k = t; k < D_CBP; k += 256) cnt[k] = 0u;
  if (t < H3_DIM) { h1s[t] = h1[t]; h2s[t] = h2[t]; }
  __syncthreads();

  for (int p = t; p < NPAIRS; p += 256) {
    const int i = p >> 7, j = p & 127;
    atomicAdd(&cnt[(h1s[i] + h2s[j]) & (D_CBP - 1)], 1u);
  }
  __syncthreads();

  // exclusive scan of padded counts; thread t owns bins 8t..8t+7
  u32 loc[8], run = 0u;
#pragma unroll
  for (int q = 0; q < 8; ++q) {
    loc[q] = run;
    run += (cnt[t * 8 + q] + 3u) & ~3u;
  }
  partial[t] = run;
  __syncthreads();
  for (int off = 1; off < 256; off <<= 1) {
    const u32 v = partial[t];
    const u32 w = (t >= off) ? partial[t - off] : 0u;
    __syncthreads();
    partial[t] = v + w;
    __syncthreads();
  }
  const u32 tbase = partial[t] - run;
#pragma unroll
  for (int q = 0; q < 8; ++q) {
    const int k = t * 8 + q;
    offs[k] = tbase + loc[q];
    cur[k]  = tbase + loc[q];
  }
  if (t == 255) offs[D_CBP] = partial[255];
  __syncthreads();

  for (int p = t; p < NPAIRS; p += 256) {
    const int i = p >> 7, j = p & 127;
    const int k = (h1s[i] + h2s[j]) & (D_CBP - 1);
    const u32 pos = atomicAdd(&cur[k], 1u);
    pairs[pos] = (u32)(i * 128 + (j ^ ((i & 7) << 2)));
  }
  __syncthreads();

#pragma unroll
  for (int q = 0; q < 8; ++q) {
    const int k = t * 8 + q;
    const u32 b = tbase + loc[q];
    const u32 c = cnt[k];
    for (u32 p = b + c; p < b + ((c + 3u) & ~3u); ++p) pairs[p] = DUMMY_IDX;
  }
}

// ---------------------------------------------------------------------------
// CBP via per-row outer product + CSR gather:
//   O[i][j] = (s1_i*ex_i) * (s2_j*ec_j)   (LDS, XOR-swizzled stores)
//   cbp[b,k] = sum over CSR bin k of O[pair]
// Thread t owns bins 8t..8t+7 (contiguous pairs in CSR -> L1-friendly).
// ---------------------------------------------------------------------------
__global__ __launch_bounds__(256) void cbp_kernel(
    const u16* __restrict__ E3,     // [2*BATCH][128] bf16
    const float* __restrict__ s1, const float* __restrict__ s2,
    const u32* __restrict__ pairs, const u32* __restrict__ offs,
    u16* __restrict__ cbp)          // [BATCH][2048] bf16
{
  __shared__ __align__(16) float O[16388];   // 128*128 + dummy slot
  __shared__ __align__(16) float af[H3_DIM], bf[H3_DIM];

  const int b = blockIdx.x, t = threadIdx.x;

  if (t < H3_DIM) {
    af[t] = b2f(E3[(size_t)b * H3_DIM + t]) * s1[t];
  } else {
    const int j = t - H3_DIM;
    bf[j] = b2f(E3[(size_t)(BATCH + b) * H3_DIM + j]) * s2[j];
  }
  if (t == 0) O[DUMMY_IDX] = 0.f;
  __syncthreads();

  // outer product: thread t -> row i = t>>1, j-half jb = (t&1)*64
  {
    const int i = t >> 1, jb = (t & 1) << 6;
    const int x = (i & 7) << 2;              // granule XOR (banks spread)
    const float ai = af[i];
    float* orow = &O[i * 128 + jb];
    const float* brow = &bf[jb];
#pragma unroll
    for (int g = 0; g < 16; ++g) {
      const float4 bv = *(const float4*)&brow[g * 4];
      float4 ov;
      ov.x = ai * bv.x; ov.y = ai * bv.y; ov.z = ai * bv.z; ov.w = ai * bv.w;
      *(float4*)&orow[(g * 4) ^ x] = ov;
    }
  }
  __syncthreads();

  u32 o[9];
#pragma unroll
  for (int r = 0; r < 9; ++r) o[r] = offs[t * 8 + r];

  float accv[8];
  int r = 0;
  float s = 0.f;
  u32 onext = o[1];
  for (u32 p = o[0]; p < o[8]; p += 4) {
    while (p >= onext) { accv[r++] = s; s = 0.f; onext = o[r + 1]; }
    const uint4 pr = *(const uint4*)&pairs[p];
    s += (O[pr.x] + O[pr.y]) + (O[pr.z] + O[pr.w]);
  }
  accv[r++] = s;
  while (r < 8) accv[r++] = 0.f;

  v8s ov;
#pragma unroll
  for (int c = 0; c < 8; ++c) ov[c] = (short)f2b(accv[c]);
  *(v8s*)(cbp + (size_t)b * D_CBP + t * 8) = ov;
}

// ---------------------------------------------------------------------------
// Head: logits = Z[B,1024](bf16) @ Wc2[1024,10] + bc2; softmax -> fp32 out.
// ---------------------------------------------------------------------------
__global__ __launch_bounds__(256) void head_softmax(
    const u16* __restrict__ Z, const float* __restrict__ Wc2,
    const float* __restrict__ bc2, float* __restrict__ out)
{
  const int row  = blockIdx.x * 4 + (threadIdx.x >> 6);
  const int lane = threadIdx.x & 63;

  float acc[CLASSES];
#pragma unroll
  for (int c = 0; c < CLASSES; ++c) acc[c] = 0.f;

  const u16* z = Z + (size_t)row * H_C;
  for (int k = lane; k < H_C; k += 64) {
    const float zv = b2f(z[k]);
    const float* w = Wc2 + (size_t)k * CLASSES;
#pragma unroll
    for (int c = 0; c < CLASSES; ++c) acc[c] += zv * w[c];
  }
#pragma unroll
  for (int c = 0; c < CLASSES; ++c) {
#pragma unroll
    for (int off = 32; off > 0; off >>= 1)
      acc[c] += __shfl_down(acc[c], off);
  }
  if (lane == 0) {
    float l[CLASSES], mx = -1e30f;
#pragma unroll
    for (int c = 0; c < CLASSES; ++c) { l[c] = acc[c] + bc2[c]; mx = fmaxf(mx, l[c]); }
    float s = 0.f;
#pragma unroll
    for (int c = 0; c < CLASSES; ++c) { l[c] = __expf(l[c] - mx); s += l[c]; }
    const float inv = 1.f / s;
#pragma unroll
    for (int c = 0; c < CLASSES; ++c) out[(size_t)row * CLASSES + c] = l[c] * inv;
  }
}

// ---------------------------------------------------------------------------
// Launcher.  Workspace (1 MiB = 1<<20), lifetime-packed, ~128 MiB:
//   Xb   @ 0       [32768,1024] bf16 = 64 MiB   (dead after G1)
//   CBPb @ 0       [16384,2048] bf16 = 64 MiB   (overlays Xb)
//   E1b  @ 64 MiB  [32768, 512] bf16 = 32 MiB   (dead after G2)
//   Zb   @ 64 MiB  [16384,1024] bf16 = 32 MiB   (overlays E1b)
//   E2b  @ 96 MiB  [32768, 256] bf16 = 16 MiB
//   E3b  @ 112 MiB [32768, 128] bf16 =  8 MiB
//   W1t @120M  W2t @121M  W3t @121.5M  Wc1t @122M (bf16, transposed)
//   pairs @126M (88 KiB)   offs @127M (8.2 KiB)
// ---------------------------------------------------------------------------
extern "C" void kernel_launch(void* const* d_in, const int* in_sizes, int n_in,
                              void* d_out, int out_size, void* d_ws, size_t ws_size,
                              hipStream_t stream) {
  const float* X       = (const float*)d_in[0];
  const float* Centers = (const float*)d_in[1];
  const float* W1      = (const float*)d_in[2];
  const float* b1      = (const float*)d_in[3];
  const float* W2      = (const float*)d_in[4];
  const float* b2      = (const float*)d_in[5];
  const float* W3      = (const float*)d_in[6];
  const float* b3      = (const float*)d_in[7];
  const int*   h1      = (const int*)d_in[8];
  const float* s1      = (const float*)d_in[9];
  const int*   h2      = (const int*)d_in[10];
  const float* s2      = (const float*)d_in[11];
  const float* Wc1     = (const float*)d_in[12];
  const float* bc1     = (const float*)d_in[13];
  const float* Wc2     = (const float*)d_in[14];
  const float* bc2     = (const float*)d_in[15];
  float* out = (float*)d_out;

  char* ws = (char*)d_ws;
  const size_t MB = 1u << 20;
  u16* Xb    = (u16*)(ws);
  u16* CBPb  = (u16*)(ws);
  u16* E1b   = (u16*)(ws + 64 * MB);
  u16* Zb    = (u16*)(ws + 64 * MB);
  u16* E2b   = (u16*)(ws + 96 * MB);
  u16* E3b   = (u16*)(ws + 112 * MB);
  u16* W1t   = (u16*)(ws + 120 * MB);
  u16* W2t   = (u16*)(ws + 121 * MB);
  u16* W3t   = (u16*)(ws + 121 * MB + 512 * 1024);
  u16* Wc1t  = (u16*)(ws + 122 * MB);
  u32* pairs = (u32*)(ws + 126 * MB);
  u32* offs  = (u32*)(ws + 127 * MB);

  const dim3 blk(256);

  // CSR for CBP (input-constant per launch)
  build_csr<<<dim3(1), blk, 0, stream>>>(h1, h2, pairs, offs);

  // casts: X, Centers -> Xb rows [0..B), [B..2B)
  cast_bf16<<<dim3((BATCH * D_IN / 4 + 255) / 256), blk, 0, stream>>>(
      X, Xb, BATCH * D_IN / 4);
  cast_bf16<<<dim3((BATCH * D_IN / 4 + 255) / 256), blk, 0, stream>>>(
      Centers, Xb + (size_t)BATCH * D_IN, BATCH * D_IN / 4);

  // weight transposes
  transpose_cast<<<dim3(D_IN / 32, H1_DIM / 32), blk, 0, stream>>>(W1, W1t, D_IN, H1_DIM);
  transpose_cast<<<dim3(H1_DIM / 32, H2_DIM / 32), blk, 0, stream>>>(W2, W2t, H1_DIM, H2_DIM);
  transpose_cast<<<dim3(H2_DIM / 32, H3_DIM / 32), blk, 0, stream>>>(W3, W3t, H2_DIM, H3_DIM);
  transpose_cast<<<dim3(D_CBP / 32, H_C / 32), blk, 0, stream>>>(Wc1, Wc1t, D_CBP, H_C);

  // G1..G3 (embed, X and Centers batched as 2B rows)
  gemm_bf16<<<dim3(H1_DIM / 128, 2 * BATCH / 128), blk, 0, stream>>>(
      Xb, W1t, b1, E1b, 2 * BATCH, H1_DIM, D_IN);
  gemm_bf16<<<dim3(H2_DIM / 128, 2 * BATCH / 128), blk, 0, stream>>>(
      E1b, W2t, b2, E2b, 2 * BATCH, H2_DIM, H1_DIM);
  gemm_bf16<<<dim3(H3_DIM / 128, 2 * BATCH / 128), blk, 0, stream>>>(
      E2b, W3t, b3, E3b, 2 * BATCH, H3_DIM, H2_DIM);

  // CBP
  cbp_kernel<<<dim3(BATCH), blk, 0, stream>>>(E3b, s1, s2, pairs, offs, CBPb);

  // G4
  gemm_bf16<<<dim3(H_C / 128, BATCH / 128), blk, 0, stream>>>(
      CBPb, Wc1t, bc1, Zb, BATCH, H_C, D_CBP);

  // head
  head_softmax<<<dim3(BATCH / 4), blk, 0, stream>>>(Zb, Wc2, bc2, out);
}

// Round 6
// 627.723 us; speedup vs baseline: 1.2519x; 1.2519x over previous
//
#include <hip/hip_runtime.h>
#include <hip/hip_bf16.h>
#include <math.h>

// ---------------------------------------------------------------------------
// Dims (fixed per reference)
// ---------------------------------------------------------------------------
#define BATCH   16384
#define D_IN    1024
#define H1_DIM  512
#define H2_DIM  256
#define H3_DIM  128
#define D_CBP   2048
#define H_C     1024
#define CLASSES 10
#define SLOPE   0.2f

typedef short v8s __attribute__((ext_vector_type(8)));
typedef float v4f __attribute__((ext_vector_type(4)));
typedef _Float16 h2v __attribute__((ext_vector_type(2)));
typedef _Float16 h8v __attribute__((ext_vector_type(8)));
typedef unsigned short u16;
typedef unsigned int   u32;

__device__ __forceinline__ float b2f(unsigned short u) {
  return __uint_as_float(((unsigned)u) << 16);
}
__device__ __forceinline__ u16 f2b(float f) {
  __hip_bfloat16 h = __float2bfloat16(f);   // RNE
  return __builtin_bit_cast(unsigned short, h);
}

// async 16B global->LDS (direct-to-shared DMA). LDS dest = wave-uniform base
// + lane*16 -> LDS layout is forced packed lane-order.
__device__ __forceinline__ void g2l16(const void* g, void* l) {
  __builtin_amdgcn_global_load_lds(
      (const __attribute__((address_space(1))) void*)g,
      (__attribute__((address_space(3))) void*)l, 16, 0, 0);
}

// ---------------------------------------------------------------------------
// bf16 MFMA GEMM (m97 structure): C[M,N] = lrelu(A[M,K] @ Bt[N,K]^T + bias)
// Tile 128x128, BK=32, 256 threads (4 waves, 2x2 of 64x64), 16 MFMA/wave/step.
// Granule rotation swizzle applied at the GLOBAL address so both A- and
// B-fragment ds_read_b128 are exactly 2 lanes/bank (free).
// ---------------------------------------------------------------------------
__global__ __launch_bounds__(256) void gemm_bf16(
    const u16* __restrict__ A,   // [M][K] bf16
    const u16* __restrict__ Bt,  // [N][K] bf16  (weights pre-transposed)
    const float* __restrict__ bias,
    u16* __restrict__ C,         // [M][N] bf16
    int M, int N, int K)
{
  __shared__ __align__(16) short Asb[128 * 32];
  __shared__ __align__(16) short Bsb[128 * 32];

  const int tid  = threadIdx.x;
  const int wave = tid >> 6, lane = tid & 63;
  const int wm = wave >> 1, wn = wave & 1;
  const int u = lane & 15, quad = lane >> 4;
  const int m0 = blockIdx.y * 128, n0 = blockIdx.x * 128;

  const int g_log = ((lane & 3) - ((lane >> 3) & 3)) & 3;
  const int srow  = wave * 32 + (lane >> 2);
  const u16* gA0 = A  + (size_t)(m0 + srow)      * K + g_log * 8;
  const u16* gA1 = A  + (size_t)(m0 + srow + 16) * K + g_log * 8;
  const u16* gB0 = Bt + (size_t)(n0 + srow)      * K + g_log * 8;
  const u16* gB1 = Bt + (size_t)(n0 + srow + 16) * K + g_log * 8;
  short* lA0 = &Asb[(wave * 32)      * 32];
  short* lA1 = &Asb[(wave * 32 + 16) * 32];
  short* lB0 = &Bsb[(wave * 32)      * 32];
  short* lB1 = &Bsb[(wave * 32 + 16) * 32];

  const int gran = (quad + (u >> 1)) & 3;
  int offA[4], offB[4];
#pragma unroll
  for (int i = 0; i < 4; ++i) {
    offA[i] = (wm * 64 + i * 16 + u) * 32 + gran * 8;
    offB[i] = (wn * 64 + i * 16 + u) * 32 + gran * 8;
  }

  v4f acc[4][4];
#pragma unroll
  for (int i = 0; i < 4; ++i)
#pragma unroll
    for (int j = 0; j < 4; ++j) acc[i][j] = (v4f){0.f, 0.f, 0.f, 0.f};

  for (int k0 = 0; k0 < K; k0 += 32) {
    __syncthreads();
    g2l16(gA0 + k0, lA0);
    g2l16(gA1 + k0, lA1);
    g2l16(gB0 + k0, lB0);
    g2l16(gB1 + k0, lB1);
    __syncthreads();
    v8s a[4], b[4];
#pragma unroll
    for (int i = 0; i < 4; ++i) a[i] = *(const v8s*)&Asb[offA[i]];
#pragma unroll
    for (int j = 0; j < 4; ++j) b[j] = *(const v8s*)&Bsb[offB[j]];
#pragma unroll
    for (int i = 0; i < 4; ++i)
#pragma unroll
      for (int j = 0; j < 4; ++j)
        acc[i][j] = __builtin_amdgcn_mfma_f32_16x16x32_bf16(a[i], b[j], acc[i][j], 0, 0, 0);
  }

  // C/D layout (m89-verified): col = lane&15, row = quad*4 + reg
  float bcol[4];
#pragma unroll
  for (int j = 0; j < 4; ++j) bcol[j] = bias[n0 + wn * 64 + j * 16 + u];
#pragma unroll
  for (int i = 0; i < 4; ++i)
#pragma unroll
    for (int r = 0; r < 4; ++r) {
      const size_t ro = (size_t)(m0 + wm * 64 + i * 16 + quad * 4 + r) * N
                        + n0 + wn * 64 + u;
#pragma unroll
      for (int j = 0; j < 4; ++j) {
        float v = acc[i][j][r] + bcol[j];
        v = v >= 0.f ? v : SLOPE * v;
        C[ro + j * 16] = f2b(v);
      }
    }
}

// ---------------------------------------------------------------------------
// cast fp32 -> bf16
// ---------------------------------------------------------------------------
__global__ __launch_bounds__(256) void cast_bf16(
    const float* __restrict__ src, u16* __restrict__ dst, int n4)
{
  const int i = blockIdx.x * 256 + threadIdx.x;
  if (i < n4) {
    const float4 v = ((const float4*)src)[i];
    __align__(8) u16 o[4] = {f2b(v.x), f2b(v.y), f2b(v.z), f2b(v.w)};
    *(uint2*)(dst + (size_t)i * 4) = *(uint2*)o;
  }
}

// ---------------------------------------------------------------------------
// transpose + cast: W[K][N] fp32 -> Wt[N][K] bf16.
// ---------------------------------------------------------------------------
__global__ __launch_bounds__(256) void transpose_cast(
    const float* __restrict__ W, u16* __restrict__ Wt, int K, int N)
{
  __shared__ float tile[32][33];
  const int k0 = blockIdx.x * 32, n0 = blockIdx.y * 32;
  const int tx = threadIdx.x & 31, ty = threadIdx.x >> 5;
#pragma unroll
  for (int s = 0; s < 4; ++s) {
    const int k = ty * 4 + s;
    tile[k][tx] = W[(size_t)(k0 + k) * N + n0 + tx];
  }
  __syncthreads();
#pragma unroll
  for (int s = 0; s < 4; ++s) {
    const int n = ty * 4 + s;
    Wt[(size_t)(n0 + n) * K + k0 + tx] = f2b(tile[tx][n]);
  }
}

// ---------------------------------------------------------------------------
// Compact bilinear pooling, gather form, f16 tables + packed-f16 FMA:
//   bsk[q]   = sum_j s2[j]*ec[b,j]*[h2[j]==q]          (f32, tiny scatter)
//   rot_r[q] = f16(bsk[(q-r) & 2047])   r = 0..7       (8 tables, 32 KiB)
//   cbp[b,k] = sum_i a_i * bsk[(k - h1_i) & 2047],  a_i = s1[i]*ex[b,i]
// Thread t owns k = 8t..8t+7: per i one aligned ds_read_b128 (8 f16) +
// 4 v_pk_fma_f16 against a_i broadcast (readlane of packed half2).
// h1[i] is wave-uniform -> scalar loads (zero VALU). f16 accumulators are
// flushed to f32 every 16 i to bound rounding error.
// ---------------------------------------------------------------------------
__global__ __launch_bounds__(256) void cbp_kernel(
    const u16* __restrict__ E3,     // [2*BATCH][128] bf16
    const int* __restrict__ h1, const float* __restrict__ s1,
    const int* __restrict__ h2, const float* __restrict__ s2,
    u16* __restrict__ cbp)          // [BATCH][2048] bf16
{
  __shared__ float bsk[D_CBP];
  __shared__ __align__(16) _Float16 rot[8][D_CBP];   // 32 KiB

  const int b = blockIdx.x, t = threadIdx.x, lane = t & 63;

  for (int q = t; q < D_CBP; q += 256) bsk[q] = 0.f;

  // a-side: value duplicated into a packed half2, two per lane
  const float a0 = b2f(E3[(size_t)b * H3_DIM + lane])      * s1[lane];
  const float a1 = b2f(E3[(size_t)b * H3_DIM + 64 + lane]) * s1[64 + lane];
  const u32 pa0 = __builtin_bit_cast(u32, (h2v){(_Float16)a0, (_Float16)a0});
  const u32 pa1 = __builtin_bit_cast(u32, (h2v){(_Float16)a1, (_Float16)a1});

  __syncthreads();
  if (t < H3_DIM) {
    const float bv = b2f(E3[(size_t)(BATCH + b) * H3_DIM + t]) * s2[t];
    atomicAdd(&bsk[h2[t]], bv);     // 128 adds, negligible contention
  }
  __syncthreads();
  // build 8 rotated f16 tables, pairwise (one b32 write per 2 entries)
  for (int p = t; p < 4 * D_CBP; p += 256) {
    const int r = p >> 10, q = (p << 1) & (D_CBP - 1);
    const float lo = bsk[(q - r) & (D_CBP - 1)];
    const float hi = bsk[(q + 1 - r) & (D_CBP - 1)];
    *(h2v*)&rot[r][q] = __builtin_bit_cast(h2v, __builtin_amdgcn_cvt_pkrtz(lo, hi));
  }
  __syncthreads();

  float facc[8];
#pragma unroll
  for (int c = 0; c < 8; ++c) facc[c] = 0.f;

  const int tb = t << 4;   // this thread's granule byte offset (g*16)
  const char* rbase = (const char*)&rot[0][0];

#pragma unroll
  for (int b16 = 0; b16 < 8; ++b16) {       // 8 chunks x 16 i
    h2v acc2[4];
#pragma unroll
    for (int c = 0; c < 4; ++c) acc2[c] = (h2v){(_Float16)0.f, (_Float16)0.f};
#pragma unroll
    for (int ii = 0; ii < 16; ++ii) {
      const int i = b16 * 16 + ii;
      const int h = h1[i];                  // uniform -> s_load, no VALU
      const u32 au = (i < 64) ? __builtin_amdgcn_readlane(pa0, i)
                              : __builtin_amdgcn_readlane(pa1, i - 64);
      const h2v a2 = __builtin_bit_cast(h2v, au);
      const int off = ((tb - ((h >> 3) << 4)) & 4095) + ((h & 7) << 12);
      const h8v tv = *(const h8v*)(rbase + off);
      const h2v* tp = (const h2v*)&tv;
#pragma unroll
      for (int c = 0; c < 4; ++c) acc2[c] += a2 * tp[c];   // v_pk_fma_f16
    }
#pragma unroll
    for (int c = 0; c < 4; ++c) {
      facc[2 * c]     += (float)acc2[c][0];
      facc[2 * c + 1] += (float)acc2[c][1];
    }
  }

  v8s ov;
#pragma unroll
  for (int c = 0; c < 8; ++c) ov[c] = (short)f2b(facc[c]);
  *(v8s*)(cbp + (size_t)b * D_CBP + t * 8) = ov;
}

// ---------------------------------------------------------------------------
// Head: logits = Z[B,1024](bf16) @ Wc2[1024,10] + bc2; softmax -> fp32 out.
// ---------------------------------------------------------------------------
__global__ __launch_bounds__(256) void head_softmax(
    const u16* __restrict__ Z, const float* __restrict__ Wc2,
    const float* __restrict__ bc2, float* __restrict__ out)
{
  const int row  = blockIdx.x * 4 + (threadIdx.x >> 6);
  const int lane = threadIdx.x & 63;

  float acc[CLASSES];
#pragma unroll
  for (int c = 0; c < CLASSES; ++c) acc[c] = 0.f;

  const u16* z = Z + (size_t)row * H_C;
  for (int k = lane; k < H_C; k += 64) {
    const float zv = b2f(z[k]);
    const float* w = Wc2 + (size_t)k * CLASSES;
#pragma unroll
    for (int c = 0; c < CLASSES; ++c) acc[c] += zv * w[c];
  }
#pragma unroll
  for (int c = 0; c < CLASSES; ++c) {
#pragma unroll
    for (int off = 32; off > 0; off >>= 1)
      acc[c] += __shfl_down(acc[c], off);
  }
  if (lane == 0) {
    float l[CLASSES], mx = -1e30f;
#pragma unroll
    for (int c = 0; c < CLASSES; ++c) { l[c] = acc[c] + bc2[c]; mx = fmaxf(mx, l[c]); }
    float s = 0.f;
#pragma unroll
    for (int c = 0; c < CLASSES; ++c) { l[c] = __expf(l[c] - mx); s += l[c]; }
    const float inv = 1.f / s;
#pragma unroll
    for (int c = 0; c < CLASSES; ++c) out[(size_t)row * CLASSES + c] = l[c] * inv;
  }
}

// ---------------------------------------------------------------------------
// Launcher.  Workspace (1 MiB = 1<<20), lifetime-packed, ~126 MiB:
//   Xb   @ 0       [32768,1024] bf16 = 64 MiB   (dead after G1)
//   CBPb @ 0       [16384,2048] bf16 = 64 MiB   (overlays Xb)
//   E1b  @ 64 MiB  [32768, 512] bf16 = 32 MiB   (dead after G2)
//   Zb   @ 64 MiB  [16384,1024] bf16 = 32 MiB   (overlays E1b)
//   E2b  @ 96 MiB  [32768, 256] bf16 = 16 MiB
//   E3b  @ 112 MiB [32768, 128] bf16 =  8 MiB
//   W1t @120M  W2t @121M  W3t @121.5M  Wc1t @122M (bf16, transposed)
// ---------------------------------------------------------------------------
extern "C" void kernel_launch(void* const* d_in, const int* in_sizes, int n_in,
                              void* d_out, int out_size, void* d_ws, size_t ws_size,
                              hipStream_t stream) {
  const float* X       = (const float*)d_in[0];
  const float* Centers = (const float*)d_in[1];
  const float* W1      = (const float*)d_in[2];
  const float* b1      = (const float*)d_in[3];
  const float* W2      = (const float*)d_in[4];
  const float* b2      = (const float*)d_in[5];
  const float* W3      = (const float*)d_in[6];
  const float* b3      = (const float*)d_in[7];
  const int*   h1      = (const int*)d_in[8];
  const float* s1      = (const float*)d_in[9];
  const int*   h2      = (const int*)d_in[10];
  const float* s2      = (const float*)d_in[11];
  const float* Wc1     = (const float*)d_in[12];
  const float* bc1     = (const float*)d_in[13];
  const float* Wc2     = (const float*)d_in[14];
  const float* bc2     = (const float*)d_in[15];
  float* out = (float*)d_out;

  char* ws = (char*)d_ws;
  const size_t MB = 1u << 20;
  u16* Xb    = (u16*)(ws);
  u16* CBPb  = (u16*)(ws);
  u16* E1b   = (u16*)(ws + 64 * MB);
  u16* Zb    = (u16*)(ws + 64 * MB);
  u16* E2b   = (u16*)(ws + 96 * MB);
  u16* E3b   = (u16*)(ws + 112 * MB);
  u16* W1t   = (u16*)(ws + 120 * MB);
  u16* W2t   = (u16*)(ws + 121 * MB);
  u16* W3t   = (u16*)(ws + 121 * MB + 512 * 1024);
  u16* Wc1t  = (u16*)(ws + 122 * MB);

  const dim3 blk(256);

  // casts: X, Centers -> Xb rows [0..B), [B..2B)
  cast_bf16<<<dim3((BATCH * D_IN / 4 + 255) / 256), blk, 0, stream>>>(
      X, Xb, BATCH * D_IN / 4);
  cast_bf16<<<dim3((BATCH * D_IN / 4 + 255) / 256), blk, 0, stream>>>(
      Centers, Xb + (size_t)BATCH * D_IN, BATCH * D_IN / 4);

  // weight transposes
  transpose_cast<<<dim3(D_IN / 32, H1_DIM / 32), blk, 0, stream>>>(W1, W1t, D_IN, H1_DIM);
  transpose_cast<<<dim3(H1_DIM / 32, H2_DIM / 32), blk, 0, stream>>>(W2, W2t, H1_DIM, H2_DIM);
  transpose_cast<<<dim3(H2_DIM / 32, H3_DIM / 32), blk, 0, stream>>>(W3, W3t, H2_DIM, H3_DIM);
  transpose_cast<<<dim3(D_CBP / 32, H_C / 32), blk, 0, stream>>>(Wc1, Wc1t, D_CBP, H_C);

  // G1..G3 (embed, X and Centers batched as 2B rows)
  gemm_bf16<<<dim3(H1_DIM / 128, 2 * BATCH / 128), blk, 0, stream>>>(
      Xb, W1t, b1, E1b, 2 * BATCH, H1_DIM, D_IN);
  gemm_bf16<<<dim3(H2_DIM / 128, 2 * BATCH / 128), blk, 0, stream>>>(
      E1b, W2t, b2, E2b, 2 * BATCH, H2_DIM, H1_DIM);
  gemm_bf16<<<dim3(H3_DIM / 128, 2 * BATCH / 128), blk, 0, stream>>>(
      E2b, W3t, b3, E3b, 2 * BATCH, H3_DIM, H2_DIM);

  // CBP
  cbp_kernel<<<dim3(BATCH), blk, 0, stream>>>(E3b, h1, s1, h2, s2, CBPb);

  // G4
  gemm_bf16<<<dim3(H_C / 128, BATCH / 128), blk, 0, stream>>>(
      CBPb, Wc1t, bc1, Zb, BATCH, H_C, D_CBP);

  // head
  head_softmax<<<dim3(BATCH / 4), blk, 0, stream>>>(Zb, Wc2, bc2, out);
}

// Round 7
// 618.226 us; speedup vs baseline: 1.2711x; 1.0154x over previous
//
#include <hip/hip_runtime.h>
#include <hip/hip_bf16.h>
#include <math.h>

// ---------------------------------------------------------------------------
// Dims (fixed per reference)
// ---------------------------------------------------------------------------
#define BATCH   16384
#define D_IN    1024
#define H1_DIM  512
#define H2_DIM  256
#define H3_DIM  128
#define D_CBP   2048
#define H_C     1024
#define CLASSES 10
#define SLOPE   0.2f

typedef short v8s __attribute__((ext_vector_type(8)));
typedef float v4f __attribute__((ext_vector_type(4)));
typedef _Float16 h2v __attribute__((ext_vector_type(2)));
typedef unsigned short u16;
typedef unsigned int   u32;

__device__ __forceinline__ float b2f(unsigned short u) {
  return __uint_as_float(((unsigned)u) << 16);
}
__device__ __forceinline__ u16 f2b(float f) {
  __hip_bfloat16 h = __float2bfloat16(f);   // RNE
  return __builtin_bit_cast(unsigned short, h);
}

// async 16B global->LDS (direct-to-shared DMA). LDS dest = wave-uniform base
// + lane*16 -> LDS layout is forced packed lane-order.
__device__ __forceinline__ void g2l16(const void* g, void* l) {
  __builtin_amdgcn_global_load_lds(
      (const __attribute__((address_space(1))) void*)g,
      (__attribute__((address_space(3))) void*)l, 16, 0, 0);
}

// ---------------------------------------------------------------------------
// bf16 MFMA GEMM (m97 structure): C[M,N] = lrelu(A[M,K] @ Bt[N,K]^T + bias)
// Tile 128x128, BK=32, 256 threads (4 waves, 2x2 of 64x64), 16 MFMA/wave/step.
// Granule rotation swizzle applied at the GLOBAL address so both A- and
// B-fragment ds_read_b128 are exactly 2 lanes/bank (free).
// ---------------------------------------------------------------------------
__global__ __launch_bounds__(256) void gemm_bf16(
    const u16* __restrict__ A,   // [M][K] bf16
    const u16* __restrict__ Bt,  // [N][K] bf16  (weights pre-transposed)
    const float* __restrict__ bias,
    u16* __restrict__ C,         // [M][N] bf16
    int M, int N, int K)
{
  __shared__ __align__(16) short Asb[128 * 32];
  __shared__ __align__(16) short Bsb[128 * 32];

  const int tid  = threadIdx.x;
  const int wave = tid >> 6, lane = tid & 63;
  const int wm = wave >> 1, wn = wave & 1;
  const int u = lane & 15, quad = lane >> 4;
  const int m0 = blockIdx.y * 128, n0 = blockIdx.x * 128;

  const int g_log = ((lane & 3) - ((lane >> 3) & 3)) & 3;
  const int srow  = wave * 32 + (lane >> 2);
  const u16* gA0 = A  + (size_t)(m0 + srow)      * K + g_log * 8;
  const u16* gA1 = A  + (size_t)(m0 + srow + 16) * K + g_log * 8;
  const u16* gB0 = Bt + (size_t)(n0 + srow)      * K + g_log * 8;
  const u16* gB1 = Bt + (size_t)(n0 + srow + 16) * K + g_log * 8;
  short* lA0 = &Asb[(wave * 32)      * 32];
  short* lA1 = &Asb[(wave * 32 + 16) * 32];
  short* lB0 = &Bsb[(wave * 32)      * 32];
  short* lB1 = &Bsb[(wave * 32 + 16) * 32];

  const int gran = (quad + (u >> 1)) & 3;
  int offA[4], offB[4];
#pragma unroll
  for (int i = 0; i < 4; ++i) {
    offA[i] = (wm * 64 + i * 16 + u) * 32 + gran * 8;
    offB[i] = (wn * 64 + i * 16 + u) * 32 + gran * 8;
  }

  v4f acc[4][4];
#pragma unroll
  for (int i = 0; i < 4; ++i)
#pragma unroll
    for (int j = 0; j < 4; ++j) acc[i][j] = (v4f){0.f, 0.f, 0.f, 0.f};

  for (int k0 = 0; k0 < K; k0 += 32) {
    __syncthreads();
    g2l16(gA0 + k0, lA0);
    g2l16(gA1 + k0, lA1);
    g2l16(gB0 + k0, lB0);
    g2l16(gB1 + k0, lB1);
    __syncthreads();
    v8s a[4], b[4];
#pragma unroll
    for (int i = 0; i < 4; ++i) a[i] = *(const v8s*)&Asb[offA[i]];
#pragma unroll
    for (int j = 0; j < 4; ++j) b[j] = *(const v8s*)&Bsb[offB[j]];
#pragma unroll
    for (int i = 0; i < 4; ++i)
#pragma unroll
      for (int j = 0; j < 4; ++j)
        acc[i][j] = __builtin_amdgcn_mfma_f32_16x16x32_bf16(a[i], b[j], acc[i][j], 0, 0, 0);
  }

  // C/D layout (m89-verified): col = lane&15, row = quad*4 + reg
  float bcol[4];
#pragma unroll
  for (int j = 0; j < 4; ++j) bcol[j] = bias[n0 + wn * 64 + j * 16 + u];
#pragma unroll
  for (int i = 0; i < 4; ++i)
#pragma unroll
    for (int r = 0; r < 4; ++r) {
      const size_t ro = (size_t)(m0 + wm * 64 + i * 16 + quad * 4 + r) * N
                        + n0 + wn * 64 + u;
#pragma unroll
      for (int j = 0; j < 4; ++j) {
        float v = acc[i][j][r] + bcol[j];
        v = v >= 0.f ? v : SLOPE * v;
        C[ro + j * 16] = f2b(v);
      }
    }
}

// ---------------------------------------------------------------------------
// cast fp32 -> bf16, two sources in one launch (X then Centers)
// ---------------------------------------------------------------------------
#define CAST_NB (BATCH * D_IN / 4 / 256)   // blocks per source
__global__ __launch_bounds__(256) void cast2_bf16(
    const float* __restrict__ srcA, const float* __restrict__ srcB,
    u16* __restrict__ dst)
{
  const int bx = blockIdx.x;
  const float* s = (bx < CAST_NB) ? srcA : srcB;
  const int i = ((bx < CAST_NB) ? bx : bx - CAST_NB) * 256 + threadIdx.x;
  u16* d = dst + ((bx < CAST_NB) ? 0 : (size_t)BATCH * D_IN);
  const float4 v = ((const float4*)s)[i];
  __align__(8) u16 o[4] = {f2b(v.x), f2b(v.y), f2b(v.z), f2b(v.w)};
  *(uint2*)(d + (size_t)i * 4) = *(uint2*)o;
}

// ---------------------------------------------------------------------------
// transpose + cast, all 4 weights in one launch (z selects the matrix):
// W[K][N] fp32 -> Wt[N][K] bf16.  32x32 tiles via LDS.
// ---------------------------------------------------------------------------
__global__ __launch_bounds__(256) void transpose_cast4(
    const float* __restrict__ W1, u16* __restrict__ W1t,
    const float* __restrict__ W2, u16* __restrict__ W2t,
    const float* __restrict__ W3, u16* __restrict__ W3t,
    const float* __restrict__ Wc1, u16* __restrict__ Wc1t)
{
  __shared__ float tile[32][33];
  const int z = blockIdx.z;
  const float* W; u16* Wt; int K, N;
  if      (z == 0) { W = W1;  Wt = W1t;  K = D_IN;   N = H1_DIM; }
  else if (z == 1) { W = W2;  Wt = W2t;  K = H1_DIM; N = H2_DIM; }
  else if (z == 2) { W = W3;  Wt = W3t;  K = H2_DIM; N = H3_DIM; }
  else             { W = Wc1; Wt = Wc1t; K = D_CBP;  N = H_C;    }
  const int k0 = blockIdx.x * 32, n0 = blockIdx.y * 32;
  if (k0 >= K || n0 >= N) return;
  const int tx = threadIdx.x & 31, ty = threadIdx.x >> 5;
#pragma unroll
  for (int s = 0; s < 4; ++s) {
    const int k = ty * 4 + s;
    tile[k][tx] = W[(size_t)(k0 + k) * N + n0 + tx];
  }
  __syncthreads();
#pragma unroll
  for (int s = 0; s < 4; ++s) {
    const int n = ty * 4 + s;
    Wt[(size_t)(n0 + n) * K + k0 + tx] = f2b(tile[tx][n]);
  }
}

// ---------------------------------------------------------------------------
// Compact bilinear pooling, gather form, f16 tables + pinned v_pk_fma_f16:
//   bsk[q]   = sum_j s2[j]*ec[b,j]*[h2[j]==q]          (f32, tiny scatter)
//   rot_r[q] = f16(bsk[(q-r) & 2047])   r = 0..7       (8 tables, 32 KiB)
//   cbp[b,k] = sum_i a_i * bsk[(k - h1_i) & 2047],  a_i = s1[i]*ex[b,i]
// Thread t owns k = 8t..8t+7: per i one ds_read_b128 (8 f16) + 4 inline-asm
// v_pk_fma_f16 (r6 showed the _Float16 vector path bloats to ~27 VALU/i).
// f16 accumulators flushed to f32 every 16 i to bound rounding error.
// ---------------------------------------------------------------------------
__global__ __launch_bounds__(256) void cbp_kernel(
    const u16* __restrict__ E3,     // [2*BATCH][128] bf16
    const int* __restrict__ h1, const float* __restrict__ s1,
    const int* __restrict__ h2, const float* __restrict__ s2,
    u16* __restrict__ cbp)          // [BATCH][2048] bf16
{
  __shared__ float bsk[D_CBP];
  __shared__ __align__(16) _Float16 rot[8][D_CBP];   // 32 KiB

  const int b = blockIdx.x, t = threadIdx.x, lane = t & 63;

  for (int q = t; q < D_CBP; q += 256) bsk[q] = 0.f;

  // a-side: value duplicated into a packed half2, two per lane
  const float a0 = b2f(E3[(size_t)b * H3_DIM + lane])      * s1[lane];
  const float a1 = b2f(E3[(size_t)b * H3_DIM + 64 + lane]) * s1[64 + lane];
  const u32 pa0 = __builtin_bit_cast(u32, (h2v){(_Float16)a0, (_Float16)a0});
  const u32 pa1 = __builtin_bit_cast(u32, (h2v){(_Float16)a1, (_Float16)a1});

  __syncthreads();
  if (t < H3_DIM) {
    const float bv = b2f(E3[(size_t)(BATCH + b) * H3_DIM + t]) * s2[t];
    atomicAdd(&bsk[h2[t]], bv);     // 128 adds, negligible contention
  }
  __syncthreads();
  // build 8 rotated f16 tables, pairwise (one b32 write per 2 entries)
  for (int p = t; p < 4 * D_CBP; p += 256) {
    const int r = p >> 10, q = (p << 1) & (D_CBP - 1);
    const float lo = bsk[(q - r) & (D_CBP - 1)];
    const float hi = bsk[(q + 1 - r) & (D_CBP - 1)];
    *(h2v*)&rot[r][q] = __builtin_bit_cast(h2v, __builtin_amdgcn_cvt_pkrtz(lo, hi));
  }
  __syncthreads();

  float facc[8];
#pragma unroll
  for (int c = 0; c < 8; ++c) facc[c] = 0.f;

  const int tb = t << 4;   // this thread's granule byte offset (g*16)
  const char* rbase = (const char*)&rot[0][0];

#pragma unroll
  for (int b16 = 0; b16 < 8; ++b16) {       // 8 chunks x 16 i
    u32 acc2[4] = {0u, 0u, 0u, 0u};         // 4x packed f16 pair accumulators
#pragma unroll
    for (int ii = 0; ii < 16; ++ii) {
      const int i = b16 * 16 + ii;
      const int h = h1[i];                  // uniform -> s_load + SALU decompose
      const u32 au = (i < 64) ? (u32)__builtin_amdgcn_readlane(pa0, i)
                              : (u32)__builtin_amdgcn_readlane(pa1, i - 64);
      const int off = ((tb - ((h >> 3) << 4)) & 4095) | ((h & 7) << 12);
      const uint4 tv = *(const uint4*)(rbase + off);
      asm("v_pk_fma_f16 %0, %1, %2, %0" : "+v"(acc2[0]) : "v"(au), "v"(tv.x));
      asm("v_pk_fma_f16 %0, %1, %2, %0" : "+v"(acc2[1]) : "v"(au), "v"(tv.y));
      asm("v_pk_fma_f16 %0, %1, %2, %0" : "+v"(acc2[2]) : "v"(au), "v"(tv.z));
      asm("v_pk_fma_f16 %0, %1, %2, %0" : "+v"(acc2[3]) : "v"(au), "v"(tv.w));
    }
#pragma unroll
    for (int c = 0; c < 4; ++c) {
      const h2v av = __builtin_bit_cast(h2v, acc2[c]);
      facc[2 * c]     += (float)av[0];
      facc[2 * c + 1] += (float)av[1];
    }
  }

  v8s ov;
#pragma unroll
  for (int c = 0; c < 8; ++c) ov[c] = (short)f2b(facc[c]);
  *(v8s*)(cbp + (size_t)b * D_CBP + t * 8) = ov;
}

// ---------------------------------------------------------------------------
// Head: logits = Z[B,1024](bf16) @ Wc2[1024,10] + bc2; softmax -> fp32 out.
// ---------------------------------------------------------------------------
__global__ __launch_bounds__(256) void head_softmax(
    const u16* __restrict__ Z, const float* __restrict__ Wc2,
    const float* __restrict__ bc2, float* __restrict__ out)
{
  const int row  = blockIdx.x * 4 + (threadIdx.x >> 6);
  const int lane = threadIdx.x & 63;

  float acc[CLASSES];
#pragma unroll
  for (int c = 0; c < CLASSES; ++c) acc[c] = 0.f;

  const u16* z = Z + (size_t)row * H_C;
  for (int k = lane; k < H_C; k += 64) {
    const float zv = b2f(z[k]);
    const float* w = Wc2 + (size_t)k * CLASSES;
#pragma unroll
    for (int c = 0; c < CLASSES; ++c) acc[c] += zv * w[c];
  }
#pragma unroll
  for (int c = 0; c < CLASSES; ++c) {
#pragma unroll
    for (int off = 32; off > 0; off >>= 1)
      acc[c] += __shfl_down(acc[c], off);
  }
  if (lane == 0) {
    float l[CLASSES], mx = -1e30f;
#pragma unroll
    for (int c = 0; c < CLASSES; ++c) { l[c] = acc[c] + bc2[c]; mx = fmaxf(mx, l[c]); }
    float s = 0.f;
#pragma unroll
    for (int c = 0; c < CLASSES; ++c) { l[c] = __expf(l[c] - mx); s += l[c]; }
    const float inv = 1.f / s;
#pragma unroll
    for (int c = 0; c < CLASSES; ++c) out[(size_t)row * CLASSES + c] = l[c] * inv;
  }
}

// ---------------------------------------------------------------------------
// Launcher.  Workspace (1 MiB = 1<<20), lifetime-packed, ~126 MiB:
//   Xb   @ 0       [32768,1024] bf16 = 64 MiB   (dead after G1)
//   CBPb @ 0       [16384,2048] bf16 = 64 MiB   (overlays Xb)
//   E1b  @ 64 MiB  [32768, 512] bf16 = 32 MiB   (dead after G2)
//   Zb   @ 64 MiB  [16384,1024] bf16 = 32 MiB   (overlays E1b)
//   E2b  @ 96 MiB  [32768, 256] bf16 = 16 MiB
//   E3b  @ 112 MiB [32768, 128] bf16 =  8 MiB
//   W1t @120M  W2t @121M  W3t @121.5M  Wc1t @122M (bf16, transposed)
// ---------------------------------------------------------------------------
extern "C" void kernel_launch(void* const* d_in, const int* in_sizes, int n_in,
                              void* d_out, int out_size, void* d_ws, size_t ws_size,
                              hipStream_t stream) {
  const float* X       = (const float*)d_in[0];
  const float* Centers = (const float*)d_in[1];
  const float* W1      = (const float*)d_in[2];
  const float* b1      = (const float*)d_in[3];
  const float* W2      = (const float*)d_in[4];
  const float* b2      = (const float*)d_in[5];
  const float* W3      = (const float*)d_in[6];
  const float* b3      = (const float*)d_in[7];
  const int*   h1      = (const int*)d_in[8];
  const float* s1      = (const float*)d_in[9];
  const int*   h2      = (const int*)d_in[10];
  const float* s2      = (const float*)d_in[11];
  const float* Wc1     = (const float*)d_in[12];
  const float* bc1     = (const float*)d_in[13];
  const float* Wc2     = (const float*)d_in[14];
  const float* bc2     = (const float*)d_in[15];
  float* out = (float*)d_out;

  char* ws = (char*)d_ws;
  const size_t MB = 1u << 20;
  u16* Xb    = (u16*)(ws);
  u16* CBPb  = (u16*)(ws);
  u16* E1b   = (u16*)(ws + 64 * MB);
  u16* Zb    = (u16*)(ws + 64 * MB);
  u16* E2b   = (u16*)(ws + 96 * MB);
  u16* E3b   = (u16*)(ws + 112 * MB);
  u16* W1t   = (u16*)(ws + 120 * MB);
  u16* W2t   = (u16*)(ws + 121 * MB);
  u16* W3t   = (u16*)(ws + 121 * MB + 512 * 1024);
  u16* Wc1t  = (u16*)(ws + 122 * MB);

  const dim3 blk(256);

  // casts: X, Centers -> Xb rows [0..B), [B..2B)  (single launch)
  cast2_bf16<<<dim3(2 * CAST_NB), blk, 0, stream>>>(X, Centers, Xb);

  // weight transposes (single launch, z selects matrix)
  transpose_cast4<<<dim3(D_CBP / 32, H_C / 32, 4), blk, 0, stream>>>(
      W1, W1t, W2, W2t, W3, W3t, Wc1, Wc1t);

  // G1..G3 (embed, X and Centers batched as 2B rows)
  gemm_bf16<<<dim3(H1_DIM / 128, 2 * BATCH / 128), blk, 0, stream>>>(
      Xb, W1t, b1, E1b, 2 * BATCH, H1_DIM, D_IN);
  gemm_bf16<<<dim3(H2_DIM / 128, 2 * BATCH / 128), blk, 0, stream>>>(
      E1b, W2t, b2, E2b, 2 * BATCH, H2_DIM, H1_DIM);
  gemm_bf16<<<dim3(H3_DIM / 128, 2 * BATCH / 128), blk, 0, stream>>>(
      E2b, W3t, b3, E3b, 2 * BATCH, H3_DIM, H2_DIM);

  // CBP
  cbp_kernel<<<dim3(BATCH), blk, 0, stream>>>(E3b, h1, s1, h2, s2, CBPb);

  // G4
  gemm_bf16<<<dim3(H_C / 128, BATCH / 128), blk, 0, stream>>>(
      CBPb, Wc1t, bc1, Zb, BATCH, H_C, D_CBP);

  // head
  head_softmax<<<dim3(BATCH / 4), blk, 0, stream>>>(Zb, Wc2, bc2, out);
}

// Round 8
// 567.326 us; speedup vs baseline: 1.3851x; 1.0897x over previous
//
#include <hip/hip_runtime.h>
#include <hip/hip_bf16.h>
#include <math.h>

// ---------------------------------------------------------------------------
// Dims (fixed per reference)
// ---------------------------------------------------------------------------
#define BATCH   16384
#define D_IN    1024
#define H1_DIM  512
#define H2_DIM  256
#define H3_DIM  128
#define D_CBP   2048
#define H_C     1024
#define CLASSES 10
#define SLOPE   0.2f

typedef short v8s __attribute__((ext_vector_type(8)));
typedef float v4f __attribute__((ext_vector_type(4)));
typedef _Float16 h2v __attribute__((ext_vector_type(2)));
typedef unsigned short u16;
typedef unsigned int   u32;

__device__ __forceinline__ float b2f(unsigned short u) {
  return __uint_as_float(((unsigned)u) << 16);
}
__device__ __forceinline__ u16 f2b(float f) {
  __hip_bfloat16 h = __float2bfloat16(f);   // RNE
  return __builtin_bit_cast(unsigned short, h);
}
__device__ __forceinline__ u32 pkrtz(float lo, float hi) {
  return __builtin_bit_cast(u32, __builtin_amdgcn_cvt_pkrtz(lo, hi));
}

// async 16B global->LDS (direct-to-shared DMA). LDS dest = wave-uniform base
// + lane*16 -> LDS layout is forced packed lane-order.
__device__ __forceinline__ void g2l16(const void* g, void* l) {
  __builtin_amdgcn_global_load_lds(
      (const __attribute__((address_space(1))) void*)g,
      (__attribute__((address_space(3))) void*)l, 16, 0, 0);
}

// ---------------------------------------------------------------------------
// bf16 MFMA GEMM (m97 structure): C[M,N] = lrelu(A[M,K] @ Bt[N,K]^T + bias)
// Tile 128x128, BK=32, 256 threads (4 waves, 2x2 of 64x64), 16 MFMA/wave/step.
// Granule rotation swizzle applied at the GLOBAL address so both A- and
// B-fragment ds_read_b128 are exactly 2 lanes/bank (free).
// ---------------------------------------------------------------------------
__global__ __launch_bounds__(256) void gemm_bf16(
    const u16* __restrict__ A,   // [M][K] bf16
    const u16* __restrict__ Bt,  // [N][K] bf16  (weights pre-transposed)
    const float* __restrict__ bias,
    u16* __restrict__ C,         // [M][N] bf16
    int M, int N, int K)
{
  __shared__ __align__(16) short Asb[128 * 32];
  __shared__ __align__(16) short Bsb[128 * 32];

  const int tid  = threadIdx.x;
  const int wave = tid >> 6, lane = tid & 63;
  const int wm = wave >> 1, wn = wave & 1;
  const int u = lane & 15, quad = lane >> 4;
  const int m0 = blockIdx.y * 128, n0 = blockIdx.x * 128;

  const int g_log = ((lane & 3) - ((lane >> 3) & 3)) & 3;
  const int srow  = wave * 32 + (lane >> 2);
  const u16* gA0 = A  + (size_t)(m0 + srow)      * K + g_log * 8;
  const u16* gA1 = A  + (size_t)(m0 + srow + 16) * K + g_log * 8;
  const u16* gB0 = Bt + (size_t)(n0 + srow)      * K + g_log * 8;
  const u16* gB1 = Bt + (size_t)(n0 + srow + 16) * K + g_log * 8;
  short* lA0 = &Asb[(wave * 32)      * 32];
  short* lA1 = &Asb[(wave * 32 + 16) * 32];
  short* lB0 = &Bsb[(wave * 32)      * 32];
  short* lB1 = &Bsb[(wave * 32 + 16) * 32];

  const int gran = (quad + (u >> 1)) & 3;
  int offA[4], offB[4];
#pragma unroll
  for (int i = 0; i < 4; ++i) {
    offA[i] = (wm * 64 + i * 16 + u) * 32 + gran * 8;
    offB[i] = (wn * 64 + i * 16 + u) * 32 + gran * 8;
  }

  v4f acc[4][4];
#pragma unroll
  for (int i = 0; i < 4; ++i)
#pragma unroll
    for (int j = 0; j < 4; ++j) acc[i][j] = (v4f){0.f, 0.f, 0.f, 0.f};

  for (int k0 = 0; k0 < K; k0 += 32) {
    __syncthreads();
    g2l16(gA0 + k0, lA0);
    g2l16(gA1 + k0, lA1);
    g2l16(gB0 + k0, lB0);
    g2l16(gB1 + k0, lB1);
    __syncthreads();
    v8s a[4], b[4];
#pragma unroll
    for (int i = 0; i < 4; ++i) a[i] = *(const v8s*)&Asb[offA[i]];
#pragma unroll
    for (int j = 0; j < 4; ++j) b[j] = *(const v8s*)&Bsb[offB[j]];
#pragma unroll
    for (int i = 0; i < 4; ++i)
#pragma unroll
      for (int j = 0; j < 4; ++j)
        acc[i][j] = __builtin_amdgcn_mfma_f32_16x16x32_bf16(a[i], b[j], acc[i][j], 0, 0, 0);
  }

  // C/D layout (m89-verified): col = lane&15, row = quad*4 + reg
  float bcol[4];
#pragma unroll
  for (int j = 0; j < 4; ++j) bcol[j] = bias[n0 + wn * 64 + j * 16 + u];
#pragma unroll
  for (int i = 0; i < 4; ++i)
#pragma unroll
    for (int r = 0; r < 4; ++r) {
      const size_t ro = (size_t)(m0 + wm * 64 + i * 16 + quad * 4 + r) * N
                        + n0 + wn * 64 + u;
#pragma unroll
      for (int j = 0; j < 4; ++j) {
        float v = acc[i][j][r] + bcol[j];
        v = v >= 0.f ? v : SLOPE * v;
        C[ro + j * 16] = f2b(v);
      }
    }
}

// ---------------------------------------------------------------------------
// cast fp32 -> bf16, two sources in one launch (X then Centers)
// ---------------------------------------------------------------------------
#define CAST_NB (BATCH * D_IN / 4 / 256)   // blocks per source
__global__ __launch_bounds__(256) void cast2_bf16(
    const float* __restrict__ srcA, const float* __restrict__ srcB,
    u16* __restrict__ dst)
{
  const int bx = blockIdx.x;
  const float* s = (bx < CAST_NB) ? srcA : srcB;
  const int i = ((bx < CAST_NB) ? bx : bx - CAST_NB) * 256 + threadIdx.x;
  u16* d = dst + ((bx < CAST_NB) ? 0 : (size_t)BATCH * D_IN);
  const float4 v = ((const float4*)s)[i];
  __align__(8) u16 o[4] = {f2b(v.x), f2b(v.y), f2b(v.z), f2b(v.w)};
  *(uint2*)(d + (size_t)i * 4) = *(uint2*)o;
}

// ---------------------------------------------------------------------------
// transpose + cast, all 4 weights in one launch (z selects the matrix):
// W[K][N] fp32 -> Wt[N][K] bf16.  32x32 tiles via LDS.
// ---------------------------------------------------------------------------
__global__ __launch_bounds__(256) void transpose_cast4(
    const float* __restrict__ W1, u16* __restrict__ W1t,
    const float* __restrict__ W2, u16* __restrict__ W2t,
    const float* __restrict__ W3, u16* __restrict__ W3t,
    const float* __restrict__ Wc1, u16* __restrict__ Wc1t)
{
  __shared__ float tile[32][33];
  const int z = blockIdx.z;
  const float* W; u16* Wt; int K, N;
  if      (z == 0) { W = W1;  Wt = W1t;  K = D_IN;   N = H1_DIM; }
  else if (z == 1) { W = W2;  Wt = W2t;  K = H1_DIM; N = H2_DIM; }
  else if (z == 2) { W = W3;  Wt = W3t;  K = H2_DIM; N = H3_DIM; }
  else             { W = Wc1; Wt = Wc1t; K = D_CBP;  N = H_C;    }
  const int k0 = blockIdx.x * 32, n0 = blockIdx.y * 32;
  if (k0 >= K || n0 >= N) return;
  const int tx = threadIdx.x & 31, ty = threadIdx.x >> 5;
#pragma unroll
  for (int s = 0; s < 4; ++s) {
    const int k = ty * 4 + s;
    tile[k][tx] = W[(size_t)(k0 + k) * N + n0 + tx];
  }
  __syncthreads();
#pragma unroll
  for (int s = 0; s < 4; ++s) {
    const int n = ty * 4 + s;
    Wt[(size_t)(n0 + n) * K + k0 + tx] = f2b(tile[tx][n]);
  }
}

// ---------------------------------------------------------------------------
// Compact bilinear pooling, gather form. r7 post-mortem: DS pipe is the
// binding resource (~2140 cyc/wave, ~30% of it the table BUILDER's scalar
// LDS traffic). This version builds the 8 rotated f16 tables from a 16-float
// per-thread register window (4 aligned b128 reads + 8 b128 writes — free
// compile-time rotations in registers), cutting builder DS ~4x.
//   bsk[q]     = sum_j s2[j]*ec[b,j]*[h2[j]==q]       (f32, tiny scatter)
//   rot4[r][g] = uint4 of f16(bsk[(8g + e - r) & 2047]), e=0..7
//   cbp[b,8t+e]= sum_i a_i * bsk[(8t + e - h1_i) & 2047]
// Main loop per i: 1 ds_read_b128 (typed AS3) + 4 v_pk_fma_f16 with the
// a_i broadcast held in the single allowed SGPR operand ("s" constraint).
// ---------------------------------------------------------------------------
__global__ __launch_bounds__(256) void cbp_kernel(
    const u16* __restrict__ E3,     // [2*BATCH][128] bf16
    const int* __restrict__ h1, const float* __restrict__ s1,
    const int* __restrict__ h2, const float* __restrict__ s2,
    u16* __restrict__ cbp)          // [BATCH][2048] bf16
{
  __shared__ float bsk[D_CBP];                  // 8 KiB
  __shared__ __align__(16) uint4 rot4[8][256];  // 32 KiB

  const int b = blockIdx.x, t = threadIdx.x, lane = t & 63;

  for (int q = t; q < D_CBP; q += 256) bsk[q] = 0.f;

  // a-side: value duplicated into a packed half2, two per lane
  const float a0 = b2f(E3[(size_t)b * H3_DIM + lane])      * s1[lane];
  const float a1 = b2f(E3[(size_t)b * H3_DIM + 64 + lane]) * s1[64 + lane];
  const u32 pa0 = __builtin_bit_cast(u32, (h2v){(_Float16)a0, (_Float16)a0});
  const u32 pa1 = __builtin_bit_cast(u32, (h2v){(_Float16)a1, (_Float16)a1});

  __syncthreads();
  if (t < H3_DIM) {
    const float bv = b2f(E3[(size_t)(BATCH + b) * H3_DIM + t]) * s2[t];
    atomicAdd(&bsk[h2[t]], bv);     // 128 adds, negligible contention
  }
  __syncthreads();

  // Builder: window e[k] = bsk[(8t - 8 + k) & 2047], k = 0..15 (4 aligned
  // float4 reads, consecutive lanes -> conflict-free). Rotation r of granule
  // t = entries 8t-r..8t-r+7 = e[8-r..15-r]: register selects + 4 cvt_pkrtz.
  {
    float e[16];
#pragma unroll
    for (int c = 0; c < 4; ++c) {
      const int idx = (8 * t - 8 + 4 * c) & (D_CBP - 1);
      *(float4*)&e[4 * c] = *(const float4*)&bsk[idx];
    }
#pragma unroll
    for (int r = 0; r < 8; ++r) {
      uint4 v;
      v.x = pkrtz(e[8 - r],  e[9 - r]);
      v.y = pkrtz(e[10 - r], e[11 - r]);
      v.z = pkrtz(e[12 - r], e[13 - r]);
      v.w = pkrtz(e[14 - r], e[15 - r]);
      rot4[r][t] = v;
    }
  }
  __syncthreads();

  float facc[8];
#pragma unroll
  for (int c = 0; c < 8; ++c) facc[c] = 0.f;

#pragma unroll
  for (int b16 = 0; b16 < 8; ++b16) {       // 8 chunks x 16 i
    u32 acc2[4] = {0u, 0u, 0u, 0u};         // 4x packed f16 pair accumulators
#pragma unroll
    for (int ii = 0; ii < 16; ++ii) {
      const int i = b16 * 16 + ii;
      const int h = h1[i];                  // uniform -> s_load + SALU decompose
      const u32 au = (i < 64) ? (u32)__builtin_amdgcn_readlane(pa0, i)
                              : (u32)__builtin_amdgcn_readlane(pa1, i - 64);
      const int g = (t - (h >> 3)) & 255;
      const uint4 tv = rot4[h & 7][g];
      asm("v_pk_fma_f16 %0, %1, %2, %0" : "+v"(acc2[0]) : "s"(au), "v"(tv.x));
      asm("v_pk_fma_f16 %0, %1, %2, %0" : "+v"(acc2[1]) : "s"(au), "v"(tv.y));
      asm("v_pk_fma_f16 %0, %1, %2, %0" : "+v"(acc2[2]) : "s"(au), "v"(tv.z));
      asm("v_pk_fma_f16 %0, %1, %2, %0" : "+v"(acc2[3]) : "s"(au), "v"(tv.w));
    }
#pragma unroll
    for (int c = 0; c < 4; ++c) {
      const h2v av = __builtin_bit_cast(h2v, acc2[c]);
      facc[2 * c]     += (float)av[0];
      facc[2 * c + 1] += (float)av[1];
    }
  }

  v8s ov;
#pragma unroll
  for (int c = 0; c < 8; ++c) ov[c] = (short)f2b(facc[c]);
  *(v8s*)(cbp + (size_t)b * D_CBP + t * 8) = ov;
}

// ---------------------------------------------------------------------------
// Head: logits = Z[B,1024](bf16) @ Wc2[1024,10] + bc2; softmax -> fp32 out.
// ---------------------------------------------------------------------------
__global__ __launch_bounds__(256) void head_softmax(
    const u16* __restrict__ Z, const float* __restrict__ Wc2,
    const float* __restrict__ bc2, float* __restrict__ out)
{
  const int row  = blockIdx.x * 4 + (threadIdx.x >> 6);
  const int lane = threadIdx.x & 63;

  float acc[CLASSES];
#pragma unroll
  for (int c = 0; c < CLASSES; ++c) acc[c] = 0.f;

  const u16* z = Z + (size_t)row * H_C;
  for (int k = lane; k < H_C; k += 64) {
    const float zv = b2f(z[k]);
    const float* w = Wc2 + (size_t)k * CLASSES;
#pragma unroll
    for (int c = 0; c < CLASSES; ++c) acc[c] += zv * w[c];
  }
#pragma unroll
  for (int c = 0; c < CLASSES; ++c) {
#pragma unroll
    for (int off = 32; off > 0; off >>= 1)
      acc[c] += __shfl_down(acc[c], off);
  }
  if (lane == 0) {
    float l[CLASSES], mx = -1e30f;
#pragma unroll
    for (int c = 0; c < CLASSES; ++c) { l[c] = acc[c] + bc2[c]; mx = fmaxf(mx, l[c]); }
    float s = 0.f;
#pragma unroll
    for (int c = 0; c < CLASSES; ++c) { l[c] = __expf(l[c] - mx); s += l[c]; }
    const float inv = 1.f / s;
#pragma unroll
    for (int c = 0; c < CLASSES; ++c) out[(size_t)row * CLASSES + c] = l[c] * inv;
  }
}

// ---------------------------------------------------------------------------
// Launcher.  Workspace (1 MiB = 1<<20), lifetime-packed, ~126 MiB:
//   Xb   @ 0       [32768,1024] bf16 = 64 MiB   (dead after G1)
//   CBPb @ 0       [16384,2048] bf16 = 64 MiB   (overlays Xb)
//   E1b  @ 64 MiB  [32768, 512] bf16 = 32 MiB   (dead after G2)
//   Zb   @ 64 MiB  [16384,1024] bf16 = 32 MiB   (overlays E1b)
//   E2b  @ 96 MiB  [32768, 256] bf16 = 16 MiB
//   E3b  @ 112 MiB [32768, 128] bf16 =  8 MiB
//   W1t @120M  W2t @121M  W3t @121.5M  Wc1t @122M (bf16, transposed)
// ---------------------------------------------------------------------------
extern "C" void kernel_launch(void* const* d_in, const int* in_sizes, int n_in,
                              void* d_out, int out_size, void* d_ws, size_t ws_size,
                              hipStream_t stream) {
  const float* X       = (const float*)d_in[0];
  const float* Centers = (const float*)d_in[1];
  const float* W1      = (const float*)d_in[2];
  const float* b1      = (const float*)d_in[3];
  const float* W2      = (const float*)d_in[4];
  const float* b2      = (const float*)d_in[5];
  const float* W3      = (const float*)d_in[6];
  const float* b3      = (const float*)d_in[7];
  const int*   h1      = (const int*)d_in[8];
  const float* s1      = (const float*)d_in[9];
  const int*   h2      = (const int*)d_in[10];
  const float* s2      = (const float*)d_in[11];
  const float* Wc1     = (const float*)d_in[12];
  const float* bc1     = (const float*)d_in[13];
  const float* Wc2     = (const float*)d_in[14];
  const float* bc2     = (const float*)d_in[15];
  float* out = (float*)d_out;

  char* ws = (char*)d_ws;
  const size_t MB = 1u << 20;
  u16* Xb    = (u16*)(ws);
  u16* CBPb  = (u16*)(ws);
  u16* E1b   = (u16*)(ws + 64 * MB);
  u16* Zb    = (u16*)(ws + 64 * MB);
  u16* E2b   = (u16*)(ws + 96 * MB);
  u16* E3b   = (u16*)(ws + 112 * MB);
  u16* W1t   = (u16*)(ws + 120 * MB);
  u16* W2t   = (u16*)(ws + 121 * MB);
  u16* W3t   = (u16*)(ws + 121 * MB + 512 * 1024);
  u16* Wc1t  = (u16*)(ws + 122 * MB);

  const dim3 blk(256);

  // casts: X, Centers -> Xb rows [0..B), [B..2B)  (single launch)
  cast2_bf16<<<dim3(2 * CAST_NB), blk, 0, stream>>>(X, Centers, Xb);

  // weight transposes (single launch, z selects matrix)
  transpose_cast4<<<dim3(D_CBP / 32, H_C / 32, 4), blk, 0, stream>>>(
      W1, W1t, W2, W2t, W3, W3t, Wc1, Wc1t);

  // G1..G3 (embed, X and Centers batched as 2B rows)
  gemm_bf16<<<dim3(H1_DIM / 128, 2 * BATCH / 128), blk, 0, stream>>>(
      Xb, W1t, b1, E1b, 2 * BATCH, H1_DIM, D_IN);
  gemm_bf16<<<dim3(H2_DIM / 128, 2 * BATCH / 128), blk, 0, stream>>>(
      E1b, W2t, b2, E2b, 2 * BATCH, H2_DIM, H1_DIM);
  gemm_bf16<<<dim3(H3_DIM / 128, 2 * BATCH / 128), blk, 0, stream>>>(
      E2b, W3t, b3, E3b, 2 * BATCH, H3_DIM, H2_DIM);

  // CBP
  cbp_kernel<<<dim3(BATCH), blk, 0, stream>>>(E3b, h1, s1, h2, s2, CBPb);

  // G4
  gemm_bf16<<<dim3(H_C / 128, BATCH / 128), blk, 0, stream>>>(
      CBPb, Wc1t, bc1, Zb, BATCH, H_C, D_CBP);

  // head
  head_softmax<<<dim3(BATCH / 4), blk, 0, stream>>>(Zb, Wc2, bc2, out);
}